// Round 8
// baseline (9505.661 us; speedup 1.0000x reference)
//
#include <hip/hip_runtime.h>

#define T_STEPS 512
#define BATCH   32
#define DIM     256
#define UNITS   256
#define COLS4U  1024

typedef _Float16 half8  __attribute__((ext_vector_type(8)));
typedef _Float16 half4v __attribute__((ext_vector_type(4)));
typedef float    f32x4  __attribute__((ext_vector_type(4)));
typedef unsigned long long ull;
typedef ull      ull2   __attribute__((ext_vector_type(2)));

__device__ __forceinline__ float fsig(float x){ return 1.0f/(1.0f+__expf(-x)); }
__device__ __forceinline__ float ftanh(float x){
  float xx=fminf(fmaxf(x,-15.f),15.f);
  float e=__expf(2.f*xx);
  return (e-1.f)/(e+1.f);
}
// byte offset into a [32][256] f16 LDS plane, XOR-swizzled 16B granules (proven r2/r3)
__device__ __forceinline__ int swz(int b,int u){
  int g=u>>3; int s=(g&7)^(b&7);
  return b*512 + (g>>3)*128 + s*16 + (u&7)*2;
}
// granule index of the (col, q=l4) weight fragment within one kt-plane (4096 granules)
__device__ __forceinline__ int gran(int col,int q){
  return ((col<<2) | q) ^ ((col>>1)&7);
}

// ============================================================================
// repack: rp[dir][kt 0..7][granule][8 halfs] ; fragment = Wr[kt*32+q*8..+8][col]
// ============================================================================
__global__ __launch_bounds__(256) void repack(
    const float* __restrict__ Wr_f, const float* __restrict__ Wr_b,
    _Float16* __restrict__ rp)
{
  const int idx = blockIdx.x*256 + threadIdx.x;   // 65536 total
  const int q   = idx & 3;
  const int col = (idx>>2) & 1023;
  const int kt  = (idx>>12) & 7;
  const int dir = idx >> 15;
  const float* Wr = dir ? Wr_b : Wr_f;
  half8 v;
#pragma unroll
  for (int r=0;r<8;r++) v[r] = (_Float16)Wr[(size_t)(kt*32 + q*8 + r)*COLS4U + col];
  *(half8*)(rp + ((size_t)((dir*8 + kt)*4096 + gran(col,q)) << 3)) = v;
}

// ============================================================================
// Phase 1 (r3-proven, verbatim): xp[dir][t][col][b] fp16 = b + x@Wk
// ============================================================================
__global__ __launch_bounds__(256, 2) void xproj(
    const float* __restrict__ x,
    const float* __restrict__ Wk_f, const float* __restrict__ b_f,
    const float* __restrict__ Wk_b, const float* __restrict__ b_b,
    _Float16* __restrict__ xph)
{
  const int bx  = blockIdx.x;
  const int dir = bx >> 8;
  const int cg  = (bx >> 5) & 7;
  const int tg  = bx & 31;
  const int tid = threadIdx.x;
  const int w   = tid >> 6;
  const int lane= tid & 63;
  const int l15 = lane & 15;
  const int l4  = lane >> 4;

  const float* Wk = dir ? Wk_b : Wk_f;
  const float* bs = dir ? b_b  : b_f;

  const int col0 = cg*128 + w*32;

  half8 Bf[2][8];
  float bias[2];
#pragma unroll
  for (int nt=0; nt<2; nt++){
    const int col = col0 + nt*16 + l15;
    bias[nt] = bs[col];
#pragma unroll
    for (int kk=0; kk<8; kk++){
      half8 v;
#pragma unroll
      for (int r=0; r<8; r++) v[r] = (_Float16)Wk[(size_t)(kk*32 + l4*8 + r)*COLS4U + col];
      Bf[nt][kk] = v;
    }
  }

  for (int tt=0; tt<16; ++tt){
    const int t   = tg*16 + tt;
    const int tin = dir ? (T_STEPS-1-t) : t;

    half8 Af[2][8];
#pragma unroll
    for (int mt=0; mt<2; mt++){
      const int b = mt*16 + l15;
#pragma unroll
      for (int kk=0; kk<8; kk++){
        const float* xp_ = x + ((size_t)b*T_STEPS + tin)*DIM + kk*32 + l4*8;
        f32x4 u0 = *(const f32x4*)xp_;
        f32x4 u1 = *(const f32x4*)(xp_ + 4);
        half8 v;
        v[0]=(_Float16)u0[0]; v[1]=(_Float16)u0[1]; v[2]=(_Float16)u0[2]; v[3]=(_Float16)u0[3];
        v[4]=(_Float16)u1[0]; v[5]=(_Float16)u1[1]; v[6]=(_Float16)u1[2]; v[7]=(_Float16)u1[3];
        Af[mt][kk] = v;
      }
    }

    f32x4 acc[2][2];
#pragma unroll
    for (int nt=0; nt<2; nt++){
      f32x4 a; a[0]=bias[nt]; a[1]=bias[nt]; a[2]=bias[nt]; a[3]=bias[nt];
      acc[nt][0]=a; acc[nt][1]=a;
    }
#pragma unroll
    for (int kk=0; kk<8; kk++)
#pragma unroll
      for (int nt=0; nt<2; nt++)
#pragma unroll
        for (int mt=0; mt<2; mt++)
          acc[nt][mt] = __builtin_amdgcn_mfma_f32_16x16x32_f16(Af[mt][kk], Bf[nt][kk], acc[nt][mt], 0,0,0);

#pragma unroll
    for (int nt=0; nt<2; nt++){
      const int col = col0 + nt*16 + l15;
#pragma unroll
      for (int mt=0; mt<2; mt++){
        half4v o;
        o[0]=(_Float16)acc[nt][mt][0]; o[1]=(_Float16)acc[nt][mt][1];
        o[2]=(_Float16)acc[nt][mt][2]; o[3]=(_Float16)acc[nt][mt][3];
        *(ull*)(xph + ((size_t)(dir*T_STEPS + t)*COLS4U + col)*BATCH + mt*16 + l4*4)
            = __builtin_bit_cast(ull, o);
      }
    }
  }
}

// ============================================================================
// Phase 2: whole direction on ONE CU. 1 block/dir, 512 thr (8 waves),
// 32 units/wave. Wr tiers (register-budget-aware, 8-wave block => <=256 regs):
//   kt 0..1 -> registers (Bf, 64 VGPR)
//   kt 2..3 -> LDS stash (128 KB)
//   kt 4..7 -> streamed from L2 each step (single SA buffer, 32 VGPR)
// xp(t+1) prefetched into xpv regs (32 VGPR) right after acc-init consumes them.
// h exchange = LDS + __syncthreads only.
// ============================================================================
__global__ __launch_bounds__(512, 1) void bilstm_1cu(
    const _Float16* __restrict__ rp,
    float* __restrict__ out,
    const _Float16* __restrict__ xph)
{
  const int dir = (int)blockIdx.x;
  const int tid = threadIdx.x;
  const int w   = tid >> 6;         // 0..7
  const int lane= tid & 63;
  const int l15 = lane & 15;
  const int l4  = lane >> 4;

  __shared__ _Float16 stash[2*4096*8];   // 131072 B : kt2..3 fragments
  __shared__ _Float16 hpl[BATCH*UNITS];  // 16384 B  : single h plane (swizzled)

  int col[8];
#pragma unroll
  for (int nt=0; nt<8; nt++)
    col[nt] = (nt>>1)*256 + w*32 + (nt&1)*16 + l15;   // gate=nt>>1, un=nt&1

  const _Float16* rpd = rp + ((size_t)dir*8*4096 << 3);

  // --- one-time: reg fragments kt0..1 ---
  half8 Bf[8][2];
#pragma unroll
  for (int nt=0; nt<8; nt++)
#pragma unroll
    for (int kt=0; kt<2; kt++)
      Bf[nt][kt] = *(const half8*)(rpd + ((size_t)(kt*4096 + gran(col[nt],l4)) << 3));

  // --- one-time: stash fill kt2..3 (verbatim granule copy) ---
  for (int i=tid; i<8192; i+=512)
    *(ull2*)(stash + ((size_t)i<<3)) = *(const ull2*)(rpd + ((size_t)(2*4096 + i) << 3));

  // --- h=0 ---
  for (int i=tid; i<2048; i+=512) ((ull*)hpl)[i] = 0ull;
  __syncthreads();

  float cst[16];
#pragma unroll
  for (int i=0;i<16;i++) cst[i]=0.f;

  const _Float16* xpt = xph + (size_t)dir*T_STEPS*COLS4U*BATCH;

  // --- prologue: xp(t=0) into xpv ---
  ull xpv[16];
#pragma unroll
  for (int mt=0; mt<2; mt++)
#pragma unroll
    for (int nt=0; nt<8; nt++)
      xpv[mt*8+nt] = *(const ull*)(xpt + (size_t)0*32768 + col[nt]*32 + mt*16 + l4*4);

  for (int t=0; t<T_STEPS; ++t){
    // ---- issue stream kt4 (landed by the time reg/stash ktiles finish) ----
    half8 SA[8];
#pragma unroll
    for (int nt=0; nt<8; nt++)
      SA[nt] = *(const half8*)(rpd + ((size_t)(4*4096 + gran(col[nt],l4)) << 3));

    // ---- acc init from xpv, then immediately re-load xpv with xp(t+1) ----
    f32x4 acc[2][8];
#pragma unroll
    for (int mt=0; mt<2; mt++)
#pragma unroll
      for (int nt=0; nt<8; nt++){
        half4v hv = __builtin_bit_cast(half4v, xpv[mt*8+nt]);
        f32x4 a; a[0]=(float)hv[0]; a[1]=(float)hv[1]; a[2]=(float)hv[2]; a[3]=(float)hv[3];
        acc[mt][nt] = a;
      }
    if (t+1 < T_STEPS){
#pragma unroll
      for (int mt=0; mt<2; mt++)
#pragma unroll
        for (int nt=0; nt<8; nt++)
          xpv[mt*8+nt] = *(const ull*)(xpt + (size_t)(t+1)*32768 + col[nt]*32 + mt*16 + l4*4);
    }

    // ---- reg ktiles 0..1 ----
#pragma unroll
    for (int kt=0; kt<2; kt++){
      const int ul = kt*32 + l4*8;
      half8 a0 = *(const half8*)((const char*)hpl + swz(l15,    ul));
      half8 a1 = *(const half8*)((const char*)hpl + swz(16+l15, ul));
#pragma unroll
      for (int nt=0; nt<8; nt++){
        acc[0][nt] = __builtin_amdgcn_mfma_f32_16x16x32_f16(a0, Bf[nt][kt], acc[0][nt], 0,0,0);
        acc[1][nt] = __builtin_amdgcn_mfma_f32_16x16x32_f16(a1, Bf[nt][kt], acc[1][nt], 0,0,0);
      }
    }

    // ---- stash ktiles 2..3 ----
#pragma unroll
    for (int ks=0; ks<2; ks++){
      const int kt = 2 + ks;
      const int ul = kt*32 + l4*8;
      half8 a0 = *(const half8*)((const char*)hpl + swz(l15,    ul));
      half8 a1 = *(const half8*)((const char*)hpl + swz(16+l15, ul));
#pragma unroll
      for (int nt=0; nt<8; nt++){
        half8 bs = *(const half8*)(stash + ((size_t)(ks*4096 + gran(col[nt],l4)) << 3));
        acc[0][nt] = __builtin_amdgcn_mfma_f32_16x16x32_f16(a0, bs, acc[0][nt], 0,0,0);
        acc[1][nt] = __builtin_amdgcn_mfma_f32_16x16x32_f16(a1, bs, acc[1][nt], 0,0,0);
      }
    }

    // ---- streamed ktiles 4..7 (single SA buffer, issue-ahead at top) ----
#pragma unroll
    for (int s=4; s<8; ++s){
      const int ul = s*32 + l4*8;
      half8 a0 = *(const half8*)((const char*)hpl + swz(l15,    ul));
      half8 a1 = *(const half8*)((const char*)hpl + swz(16+l15, ul));
#pragma unroll
      for (int nt=0; nt<8; nt++){
        acc[0][nt] = __builtin_amdgcn_mfma_f32_16x16x32_f16(a0, SA[nt], acc[0][nt], 0,0,0);
        acc[1][nt] = __builtin_amdgcn_mfma_f32_16x16x32_f16(a1, SA[nt], acc[1][nt], 0,0,0);
      }
      if (s < 7){
#pragma unroll
        for (int nt=0; nt<8; nt++)
          SA[nt] = *(const half8*)(rpd + ((size_t)((s+1)*4096 + gran(col[nt],l4)) << 3));
      }
    }

    __syncthreads();   // all waves done reading h_t from hpl

    // ---- gates -> c, h ; write h_{t+1} to hpl + out stores ----
    const int tout = dir ? (T_STEPS-1-t) : t;
#pragma unroll
    for (int un=0; un<2; un++){
      const int unit = w*32 + un*16 + l15;
      const int oc   = dir*256 + unit;
#pragma unroll
      for (int mt=0; mt<2; mt++){
#pragma unroll
        for (int r=0; r<4; r++){
          const int b = mt*16 + l4*4 + r;
          float iv = fsig (acc[mt][0+un][r]);
          float fv = fsig (acc[mt][2+un][r]);
          float gv = ftanh(acc[mt][4+un][r]);
          float ov = fsig (acc[mt][6+un][r]);
          float &c = cst[(mt*2+un)*4 + r];
          c = fv*c + iv*gv;
          float hv = ov*ftanh(c);
          if (t+1 < T_STEPS)
            *(_Float16*)((char*)hpl + swz(b, unit)) = (_Float16)hv;
          out[((size_t)b*T_STEPS + tout)*(2*UNITS) + oc] = hv;
          if (t == T_STEPS-1)
            out[(size_t)BATCH*T_STEPS*(2*UNITS) + (size_t)b*(2*UNITS) + oc] = hv;
        }
      }
    }
    __syncthreads();   // h_{t+1} complete before next step's reads
  }
}

// ============================================================================
// Fallback for small ws (round-2 proven fused kernel)
// ============================================================================
__global__ __launch_bounds__(256,1) void bilstm_mfma(
    const float* __restrict__ x,
    const float* __restrict__ Wk_f, const float* __restrict__ Wr_f, const float* __restrict__ b_f,
    const float* __restrict__ Wk_b, const float* __restrict__ Wr_b, const float* __restrict__ b_b,
    float* __restrict__ out,
    unsigned short* __restrict__ slices,
    unsigned* __restrict__ flags)
{
  const int dir = blockIdx.x >> 2;
  const int g4  = blockIdx.x & 3;
  const int tid = threadIdx.x;
  const int w   = tid >> 6;
  const int lane= tid & 63;
  const int l15 = lane & 15;
  const int l4  = lane >> 4;

  const float* Wk = dir ? Wk_b : Wk_f;
  const float* Wr = dir ? Wr_b : Wr_f;
  const float* bs = dir ? b_b  : b_f;

  const int u0b   = g4*64;
  const int upl   = u0b + w*16 + l15;
  const int outcol= dir*256 + upl;

  __shared__ _Float16 xlds[BATCH*DIM];
  __shared__ _Float16 hlds[2][BATCH*UNITS];

  half8 Bf[4][16];
#pragma unroll
  for (int q=0;q<4;q++){
    const int col = q*256 + upl;
#pragma unroll
    for (int kk=0;kk<16;kk++){
      const float* Ws = (kk<8) ? Wk : Wr;
      const int k0 = (kk&7)*32 + l4*8;
      half8 v;
#pragma unroll
      for (int r=0;r<8;r++) v[r] = (_Float16)Ws[(size_t)(k0+r)*COLS4U + col];
      Bf[q][kk] = v;
      __builtin_amdgcn_sched_barrier(0);
    }
  }

  float bias[4];
#pragma unroll
  for (int q=0;q<4;q++) bias[q] = bs[q*256 + upl];

  {
    half8 z;
#pragma unroll
    for (int e=0;e<8;e++) z[e] = (_Float16)0.f;
    for (int i=tid; i<BATCH*UNITS/8; i+=256) ((half8*)hlds[0])[i] = z;
  }

  const int bx  = tid >> 3;
  const int d0x = (tid & 7) * 32;
  float xr[32];
  {
    const int tin0 = dir ? (T_STEPS-1) : 0;
    const float* xp = x + ((size_t)bx*T_STEPS + tin0)*DIM + d0x;
#pragma unroll
    for (int i=0;i<8;i++){
      f32x4 v = *(const f32x4*)(xp + i*4);
      xr[i*4+0]=v[0]; xr[i*4+1]=v[1]; xr[i*4+2]=v[2]; xr[i*4+3]=v[3];
    }
#pragma unroll
    for (int j=0;j<4;j++){
      half8 hh;
#pragma unroll
      for (int e=0;e<8;e++) hh[e] = (_Float16)xr[j*8+e];
      *(half8*)((char*)xlds + swz(bx, d0x + j*8)) = hh;
    }
  }
  __syncthreads();

  float cst[8];
#pragma unroll
  for (int i=0;i<8;i++) cst[i]=0.f;
  bool spin_ok = true;

  for (int t=0; t<T_STEPS; ++t){
    if (t+1 < T_STEPS){
      const int tin = dir ? (T_STEPS-2-t) : (t+1);
      const float* xp = x + ((size_t)bx*T_STEPS + tin)*DIM + d0x;
#pragma unroll
      for (int i=0;i<8;i++){
        f32x4 v = *(const f32x4*)(xp + i*4);
        xr[i*4+0]=v[0]; xr[i*4+1]=v[1]; xr[i*4+2]=v[2]; xr[i*4+3]=v[3];
      }
    }

    f32x4 acc[2][4];
#pragma unroll
    for (int q=0;q<4;q++){
      f32x4 a; a[0]=bias[q]; a[1]=bias[q]; a[2]=bias[q]; a[3]=bias[q];
      acc[0][q]=a; acc[1][q]=a;
    }
    const char* hpl2 = (const char*)hlds[t&1];
#pragma unroll
    for (int kk=0;kk<16;kk++){
      const char* pl = (kk<8) ? (const char*)xlds : hpl2;
      const int ul = (kk&7)*32 + l4*8;
      half8 a0 = *(const half8*)(pl + swz(l15,      ul));
      half8 a1 = *(const half8*)(pl + swz(16+l15,   ul));
#pragma unroll
      for (int q=0;q<4;q++){
        acc[0][q] = __builtin_amdgcn_mfma_f32_16x16x32_f16(a0, Bf[q][kk], acc[0][q], 0,0,0);
        acc[1][q] = __builtin_amdgcn_mfma_f32_16x16x32_f16(a1, Bf[q][kk], acc[1][q], 0,0,0);
      }
    }

    const int tout = dir ? (T_STEPS-1-t) : t;
    unsigned short* slc = slices + (((size_t)((t+1)&1))*8 + dir*4 + g4)*2048;
    char* hnx = (char*)hlds[(t+1)&1];
#pragma unroll
    for (int mt=0; mt<2; mt++){
#pragma unroll
      for (int r=0;r<4;r++){
        const int b = mt*16 + l4*4 + r;
        float iv = fsig (acc[mt][0][r]);
        float fv = fsig (acc[mt][1][r]);
        float gv = ftanh(acc[mt][2][r]);
        float ov = fsig (acc[mt][3][r]);
        float &c = cst[mt*4+r];
        c = fv*c + iv*gv;
        float hval = ov*ftanh(c);
        out[((size_t)b*T_STEPS + tout)*(2*UNITS) + outcol] = hval;
        if (t == T_STEPS-1)
          out[(size_t)BATCH*T_STEPS*(2*UNITS) + (size_t)b*(2*UNITS) + outcol] = hval;
        _Float16 hf = (_Float16)hval;
        *(_Float16*)(hnx + swz(b, upl)) = hf;
        if (t+1 < T_STEPS)
          __hip_atomic_store(&slc[b*64 + (w*16+l15)],
                             __builtin_bit_cast(unsigned short, hf),
                             __ATOMIC_RELAXED, __HIP_MEMORY_SCOPE_AGENT);
      }
    }
    __syncthreads();

    if (t+1 < T_STEPS){
      if (tid == 192)
        __hip_atomic_store(&flags[(dir*4+g4)*32], (unsigned)(t+1),
                           __ATOMIC_RELAXED, __HIP_MEMORY_SCOPE_AGENT);
#pragma unroll
      for (int j=0;j<4;j++){
        half8 hh;
#pragma unroll
        for (int e=0;e<8;e++) hh[e] = (_Float16)xr[j*8+e];
        *(half8*)((char*)xlds + swz(bx, d0x + j*8)) = hh;
      }
      if (w < 3){
        const int p = w + (w >= g4);
        const unsigned target = (unsigned)(t+1);
        if (spin_ok){
          int sp = 0;
          while (__hip_atomic_load(&flags[(dir*4+p)*32],
                                   __ATOMIC_RELAXED, __HIP_MEMORY_SCOPE_AGENT) < target){
            if (++sp > (1<<22)) { spin_ok = false; break; }
          }
        }
        const ull* src = (const ull*)(slices + (((size_t)((t+1)&1))*8 + dir*4 + p)*2048);
        const int bsl = lane >> 1;
        const int u00 = (lane & 1) * 32;
#pragma unroll
        for (int j=0;j<4;j++){
          ull v0 = __hip_atomic_load(&src[lane*8 + 2*j  ], __ATOMIC_RELAXED, __HIP_MEMORY_SCOPE_AGENT);
          ull v1 = __hip_atomic_load(&src[lane*8 + 2*j+1], __ATOMIC_RELAXED, __HIP_MEMORY_SCOPE_AGENT);
          ull2 vv; vv[0]=v0; vv[1]=v1;
          *(ull2*)(hnx + swz(bsl, p*64 + u00 + j*8)) = vv;
        }
      }
      __syncthreads();
    }
  }
}

extern "C" void kernel_launch(void* const* d_in, const int* in_sizes, int n_in,
                              void* d_out, int out_size, void* d_ws, size_t ws_size,
                              hipStream_t stream) {
  const float* x    = (const float*)d_in[0];
  const float* Wk_f = (const float*)d_in[1];
  const float* Wr_f = (const float*)d_in[2];
  const float* b_f  = (const float*)d_in[3];
  const float* Wk_b = (const float*)d_in[4];
  const float* Wr_b = (const float*)d_in[5];
  const float* b_b  = (const float*)d_in[6];
  float* out = (float*)d_out;

  const size_t XPH = (size_t)2*T_STEPS*COLS4U*BATCH*sizeof(_Float16);  // 64 MiB
  const size_t RPB = (size_t)2*8*4096*8*sizeof(_Float16);              // 1 MiB

  if (ws_size >= XPH + RPB) {
    _Float16* xph = (_Float16*)d_ws;
    _Float16* rp  = (_Float16*)((char*)d_ws + XPH);
    repack<<<256, 256, 0, stream>>>(Wr_f, Wr_b, rp);
    xproj<<<512, 256, 0, stream>>>(x, Wk_f, b_f, Wk_b, b_b, xph);
    bilstm_1cu<<<2, 512, 0, stream>>>(rp, out, xph);
  } else {
    unsigned short* slices = (unsigned short*)d_ws;
    unsigned* flags = (unsigned*)((char*)d_ws + 65536);
    hipMemsetAsync((char*)d_ws + 65536, 0, 1024, stream);
    bilstm_mfma<<<8, 256, 0, stream>>>(x, Wk_f, Wr_f, b_f, Wk_b, Wr_b, b_b,
                                       out, slices, flags);
  }
}

// Round 9
// 7510.819 us; speedup vs baseline: 1.2656x; 1.2656x over previous
//
#include <hip/hip_runtime.h>

#define T_STEPS 512
#define BATCH   32
#define DIM     256
#define UNITS   256
#define COLS4U  1024

typedef _Float16 half8  __attribute__((ext_vector_type(8)));
typedef _Float16 half4v __attribute__((ext_vector_type(4)));
typedef float    f32x4  __attribute__((ext_vector_type(4)));
typedef unsigned long long ull;
typedef ull      ull2   __attribute__((ext_vector_type(2)));

__device__ __forceinline__ float fsig(float x){ return 1.0f/(1.0f+__expf(-x)); }
__device__ __forceinline__ float ftanh(float x){
  float xx=fminf(fmaxf(x,-15.f),15.f);
  float e=__expf(2.f*xx);
  return (e-1.f)/(e+1.f);
}
// byte offset into a [rows][256] f16 LDS plane, XOR-swizzled 16B granules (proven r2/r3)
__device__ __forceinline__ int swz(int b,int u){
  int g=u>>3; int s=(g&7)^(b&7);
  return b*512 + (g>>3)*128 + s*16 + (u&7)*2;
}
// granule index of the (col, q=l4) weight fragment within one kt-plane (4096 granules)
__device__ __forceinline__ int gran(int col,int q){
  return ((col<<2) | q) ^ ((col>>1)&7);
}

// ============================================================================
// repack (r8-proven): rp[dir][kt 0..7][granule][8 halfs]
//   fragment = Wr[kt*32+q*8 .. +8][col] as fp16
// ============================================================================
__global__ __launch_bounds__(256) void repack(
    const float* __restrict__ Wr_f, const float* __restrict__ Wr_b,
    _Float16* __restrict__ rp)
{
  const int idx = blockIdx.x*256 + threadIdx.x;   // 65536 total
  const int q   = idx & 3;
  const int col = (idx>>2) & 1023;
  const int kt  = (idx>>12) & 7;
  const int dir = idx >> 15;
  const float* Wr = dir ? Wr_b : Wr_f;
  half8 v;
#pragma unroll
  for (int r=0;r<8;r++) v[r] = (_Float16)Wr[(size_t)(kt*32 + q*8 + r)*COLS4U + col];
  *(half8*)(rp + ((size_t)((dir*8 + kt)*4096 + gran(col,q)) << 3)) = v;
}

// ============================================================================
// Phase 1 (r3-proven, verbatim): xp[dir][t][col][b] fp16 = b + x@Wk
// ============================================================================
__global__ __launch_bounds__(256, 2) void xproj(
    const float* __restrict__ x,
    const float* __restrict__ Wk_f, const float* __restrict__ b_f,
    const float* __restrict__ Wk_b, const float* __restrict__ b_b,
    _Float16* __restrict__ xph)
{
  const int bx  = blockIdx.x;
  const int dir = bx >> 8;
  const int cg  = (bx >> 5) & 7;
  const int tg  = bx & 31;
  const int tid = threadIdx.x;
  const int w   = tid >> 6;
  const int lane= tid & 63;
  const int l15 = lane & 15;
  const int l4  = lane >> 4;

  const float* Wk = dir ? Wk_b : Wk_f;
  const float* bs = dir ? b_b  : b_f;

  const int col0 = cg*128 + w*32;

  half8 Bf[2][8];
  float bias[2];
#pragma unroll
  for (int nt=0; nt<2; nt++){
    const int col = col0 + nt*16 + l15;
    bias[nt] = bs[col];
#pragma unroll
    for (int kk=0; kk<8; kk++){
      half8 v;
#pragma unroll
      for (int r=0; r<8; r++) v[r] = (_Float16)Wk[(size_t)(kk*32 + l4*8 + r)*COLS4U + col];
      Bf[nt][kk] = v;
    }
  }

  for (int tt=0; tt<16; ++tt){
    const int t   = tg*16 + tt;
    const int tin = dir ? (T_STEPS-1-t) : t;

    half8 Af[2][8];
#pragma unroll
    for (int mt=0; mt<2; mt++){
      const int b = mt*16 + l15;
#pragma unroll
      for (int kk=0; kk<8; kk++){
        const float* xp_ = x + ((size_t)b*T_STEPS + tin)*DIM + kk*32 + l4*8;
        f32x4 u0 = *(const f32x4*)xp_;
        f32x4 u1 = *(const f32x4*)(xp_ + 4);
        half8 v;
        v[0]=(_Float16)u0[0]; v[1]=(_Float16)u0[1]; v[2]=(_Float16)u0[2]; v[3]=(_Float16)u0[3];
        v[4]=(_Float16)u1[0]; v[5]=(_Float16)u1[1]; v[6]=(_Float16)u1[2]; v[7]=(_Float16)u1[3];
        Af[mt][kk] = v;
      }
    }

    f32x4 acc[2][2];
#pragma unroll
    for (int nt=0; nt<2; nt++){
      f32x4 a; a[0]=bias[nt]; a[1]=bias[nt]; a[2]=bias[nt]; a[3]=bias[nt];
      acc[nt][0]=a; acc[nt][1]=a;
    }
#pragma unroll
    for (int kk=0; kk<8; kk++)
#pragma unroll
      for (int nt=0; nt<2; nt++)
#pragma unroll
        for (int mt=0; mt<2; mt++)
          acc[nt][mt] = __builtin_amdgcn_mfma_f32_16x16x32_f16(Af[mt][kk], Bf[nt][kk], acc[nt][mt], 0,0,0);

#pragma unroll
    for (int nt=0; nt<2; nt++){
      const int col = col0 + nt*16 + l15;
#pragma unroll
      for (int mt=0; mt<2; mt++){
        half4v o;
        o[0]=(_Float16)acc[nt][mt][0]; o[1]=(_Float16)acc[nt][mt][1];
        o[2]=(_Float16)acc[nt][mt][2]; o[3]=(_Float16)acc[nt][mt][3];
        *(ull*)(xph + ((size_t)(dir*T_STEPS + t)*COLS4U + col)*BATCH + mt*16 + l4*4)
            = __builtin_bit_cast(ull, o);
      }
    }
  }
}

// ============================================================================
// Phase 2: BATCH-SPLIT scan — 4 blocks (dir x batch-half), 256 thr, 1 CU each.
// Each block: 16 batches (one 16-row mtile), ALL 256 units -> zero
// inter-block communication. Wave w owns 16 ntiles (cols w*64..w*64+63 of
// each gate). Wr tiers: kt0 regs / kt1..2 LDS stash / kt3..7 streamed L2.
// ============================================================================
__global__ __launch_bounds__(256, 1) void bilstm_bsplit(
    const _Float16* __restrict__ rp,
    float* __restrict__ out,
    const _Float16* __restrict__ xph)
{
  const int dir = (int)blockIdx.x >> 1;
  const int bh  = (int)blockIdx.x & 1;
  const int tid = threadIdx.x;
  const int w   = tid >> 6;         // 0..3
  const int lane= tid & 63;
  const int l15 = lane & 15;
  const int l4  = lane >> 4;

  __shared__ _Float16 stash[2*4096*8];   // 131072 B : kt1..2 fragments
  __shared__ _Float16 hpl[16*UNITS];     // 8192 B   : h plane, 16 rows, swizzled

  int col[16];
#pragma unroll
  for (int nt=0; nt<16; nt++){
    const int q = nt>>2, j = nt&3;
    col[nt] = q*256 + w*64 + j*16 + l15;
  }

  const _Float16* rpd = rp + ((size_t)dir*8*4096 << 3);

  // --- one-time: reg fragments kt0 ---
  half8 Bf[16];
#pragma unroll
  for (int nt=0; nt<16; nt++)
    Bf[nt] = *(const half8*)(rpd + ((size_t)(0*4096 + gran(col[nt],l4)) << 3));

  // --- one-time: stash fill kt1..2 (verbatim granule copy) ---
  for (int i=tid; i<8192; i+=256)
    *(ull2*)(stash + ((size_t)i<<3)) = *(const ull2*)(rpd + ((size_t)(1*4096 + i) << 3));

  // --- h=0 ---
  for (int i=tid; i<1024; i+=256) ((ull*)hpl)[i] = 0ull;
  __syncthreads();

  float cst[16];
#pragma unroll
  for (int i=0;i<16;i++) cst[i]=0.f;

  // xph base for this (dir, batch-half): element (t,col,b) at t*32768 + col*32 + b
  const _Float16* xpt = xph + (size_t)dir*T_STEPS*COLS4U*BATCH + bh*16;

  // --- prologue: xp(t=0) and first streamed plane (kt3) ---
  ull xpv[16];
#pragma unroll
  for (int nt=0; nt<16; nt++)
    xpv[nt] = *(const ull*)(xpt + (size_t)0*32768 + col[nt]*32 + l4*4);

  half8 SA[16];
#pragma unroll
  for (int nt=0; nt<16; nt++)
    SA[nt] = *(const half8*)(rpd + ((size_t)(3*4096 + gran(col[nt],l4)) << 3));

  for (int t=0; t<T_STEPS; ++t){
    // ---- acc init from xpv (bias + x@Wk folded), then prefetch xp(t+1) ----
    f32x4 acc[16];
#pragma unroll
    for (int nt=0; nt<16; nt++){
      half4v hv = __builtin_bit_cast(half4v, xpv[nt]);
      f32x4 a; a[0]=(float)hv[0]; a[1]=(float)hv[1]; a[2]=(float)hv[2]; a[3]=(float)hv[3];
      acc[nt] = a;
    }
    if (t+1 < T_STEPS){
#pragma unroll
      for (int nt=0; nt<16; nt++)
        xpv[nt] = *(const ull*)(xpt + (size_t)(t+1)*32768 + col[nt]*32 + l4*4);
    }

    // ---- kt0 (register weights) ----
    {
      const int ul = 0*32 + l4*8;
      half8 a0 = *(const half8*)((const char*)hpl + swz(l15, ul));
#pragma unroll
      for (int nt=0; nt<16; nt++)
        acc[nt] = __builtin_amdgcn_mfma_f32_16x16x32_f16(a0, Bf[nt], acc[nt], 0,0,0);
    }

    // ---- kt1..2 (LDS stash weights) ----
#pragma unroll
    for (int ks=0; ks<2; ks++){
      const int ul = (1+ks)*32 + l4*8;
      half8 a0 = *(const half8*)((const char*)hpl + swz(l15, ul));
#pragma unroll
      for (int nt=0; nt<16; nt++){
        half8 bs = *(const half8*)(stash + ((size_t)(ks*4096 + gran(col[nt],l4)) << 3));
        acc[nt] = __builtin_amdgcn_mfma_f32_16x16x32_f16(a0, bs, acc[nt], 0,0,0);
      }
    }

    // ---- kt3..7 (streamed weights; reload overlaps current kt's MFMAs) ----
#pragma unroll
    for (int s=3; s<8; ++s){
      const int ul = s*32 + l4*8;
      half8 a0 = *(const half8*)((const char*)hpl + swz(l15, ul));
#pragma unroll
      for (int nt=0; nt<16; nt++)
        acc[nt] = __builtin_amdgcn_mfma_f32_16x16x32_f16(a0, SA[nt], acc[nt], 0,0,0);
      if (s < 7){
#pragma unroll
        for (int nt=0; nt<16; nt++)
          SA[nt] = *(const half8*)(rpd + ((size_t)((s+1)*4096 + gran(col[nt],l4)) << 3));
      } else if (t+1 < T_STEPS){
#pragma unroll
        for (int nt=0; nt<16; nt++)
          SA[nt] = *(const half8*)(rpd + ((size_t)(3*4096 + gran(col[nt],l4)) << 3));
      }
    }

    __syncthreads();   // all waves done reading h_t

    // ---- gates -> c, h ; write h_{t+1} + out ----
    const int tout = dir ? (T_STEPS-1-t) : t;
#pragma unroll
    for (int j=0; j<4; j++){
      const int unit = w*64 + j*16 + l15;
      const int oc   = dir*256 + unit;
#pragma unroll
      for (int r=0; r<4; r++){
        const int b = l4*4 + r;                 // local batch row 0..15
        float iv = fsig (acc[0*4+j][r]);
        float fv = fsig (acc[1*4+j][r]);
        float gv = ftanh(acc[2*4+j][r]);
        float ov = fsig (acc[3*4+j][r]);
        float &c = cst[j*4+r];
        c = fv*c + iv*gv;
        float hv = ov*ftanh(c);
        if (t+1 < T_STEPS)
          *(_Float16*)((char*)hpl + swz(b, unit)) = (_Float16)hv;
        const size_t B = (size_t)(bh*16 + b);
        out[(B*T_STEPS + tout)*(2*UNITS) + oc] = hv;
        if (t == T_STEPS-1)
          out[(size_t)BATCH*T_STEPS*(2*UNITS) + B*(2*UNITS) + oc] = hv;
      }
    }
    __syncthreads();   // h_{t+1} complete before next step's reads
  }
}

// ============================================================================
// Fallback for small ws (round-2 proven fused kernel)
// ============================================================================
__global__ __launch_bounds__(256,1) void bilstm_mfma(
    const float* __restrict__ x,
    const float* __restrict__ Wk_f, const float* __restrict__ Wr_f, const float* __restrict__ b_f,
    const float* __restrict__ Wk_b, const float* __restrict__ Wr_b, const float* __restrict__ b_b,
    float* __restrict__ out,
    unsigned short* __restrict__ slices,
    unsigned* __restrict__ flags)
{
  const int dir = blockIdx.x >> 2;
  const int g4  = blockIdx.x & 3;
  const int tid = threadIdx.x;
  const int w   = tid >> 6;
  const int lane= tid & 63;
  const int l15 = lane & 15;
  const int l4  = lane >> 4;

  const float* Wk = dir ? Wk_b : Wk_f;
  const float* Wr = dir ? Wr_b : Wr_f;
  const float* bs = dir ? b_b  : b_f;

  const int u0b   = g4*64;
  const int upl   = u0b + w*16 + l15;
  const int outcol= dir*256 + upl;

  __shared__ _Float16 xlds[BATCH*DIM];
  __shared__ _Float16 hlds[2][BATCH*UNITS];

  half8 Bf[4][16];
#pragma unroll
  for (int q=0;q<4;q++){
    const int col = q*256 + upl;
#pragma unroll
    for (int kk=0;kk<16;kk++){
      const float* Ws = (kk<8) ? Wk : Wr;
      const int k0 = (kk&7)*32 + l4*8;
      half8 v;
#pragma unroll
      for (int r=0;r<8;r++) v[r] = (_Float16)Ws[(size_t)(k0+r)*COLS4U + col];
      Bf[q][kk] = v;
      __builtin_amdgcn_sched_barrier(0);
    }
  }

  float bias[4];
#pragma unroll
  for (int q=0;q<4;q++) bias[q] = bs[q*256 + upl];

  {
    half8 z;
#pragma unroll
    for (int e=0;e<8;e++) z[e] = (_Float16)0.f;
    for (int i=tid; i<BATCH*UNITS/8; i+=256) ((half8*)hlds[0])[i] = z;
  }

  const int bx  = tid >> 3;
  const int d0x = (tid & 7) * 32;
  float xr[32];
  {
    const int tin0 = dir ? (T_STEPS-1) : 0;
    const float* xp = x + ((size_t)bx*T_STEPS + tin0)*DIM + d0x;
#pragma unroll
    for (int i=0;i<8;i++){
      f32x4 v = *(const f32x4*)(xp + i*4);
      xr[i*4+0]=v[0]; xr[i*4+1]=v[1]; xr[i*4+2]=v[2]; xr[i*4+3]=v[3];
    }
#pragma unroll
    for (int j=0;j<4;j++){
      half8 hh;
#pragma unroll
      for (int e=0;e<8;e++) hh[e] = (_Float16)xr[j*8+e];
      *(half8*)((char*)xlds + swz(bx, d0x + j*8)) = hh;
    }
  }
  __syncthreads();

  float cst[8];
#pragma unroll
  for (int i=0;i<8;i++) cst[i]=0.f;
  bool spin_ok = true;

  for (int t=0; t<T_STEPS; ++t){
    if (t+1 < T_STEPS){
      const int tin = dir ? (T_STEPS-2-t) : (t+1);
      const float* xp = x + ((size_t)bx*T_STEPS + tin)*DIM + d0x;
#pragma unroll
      for (int i=0;i<8;i++){
        f32x4 v = *(const f32x4*)(xp + i*4);
        xr[i*4+0]=v[0]; xr[i*4+1]=v[1]; xr[i*4+2]=v[2]; xr[i*4+3]=v[3];
      }
    }

    f32x4 acc[2][4];
#pragma unroll
    for (int q=0;q<4;q++){
      f32x4 a; a[0]=bias[q]; a[1]=bias[q]; a[2]=bias[q]; a[3]=bias[q];
      acc[0][q]=a; acc[1][q]=a;
    }
    const char* hpl2 = (const char*)hlds[t&1];
#pragma unroll
    for (int kk=0;kk<16;kk++){
      const char* pl = (kk<8) ? (const char*)xlds : hpl2;
      const int ul = (kk&7)*32 + l4*8;
      half8 a0 = *(const half8*)(pl + swz(l15,      ul));
      half8 a1 = *(const half8*)(pl + swz(16+l15,   ul));
#pragma unroll
      for (int q=0;q<4;q++){
        acc[0][q] = __builtin_amdgcn_mfma_f32_16x16x32_f16(a0, Bf[q][kk], acc[0][q], 0,0,0);
        acc[1][q] = __builtin_amdgcn_mfma_f32_16x16x32_f16(a1, Bf[q][kk], acc[1][q], 0,0,0);
      }
    }

    const int tout = dir ? (T_STEPS-1-t) : t;
    unsigned short* slc = slices + (((size_t)((t+1)&1))*8 + dir*4 + g4)*2048;
    char* hnx = (char*)hlds[(t+1)&1];
#pragma unroll
    for (int mt=0; mt<2; mt++){
#pragma unroll
      for (int r=0;r<4;r++){
        const int b = mt*16 + l4*4 + r;
        float iv = fsig (acc[mt][0][r]);
        float fv = fsig (acc[mt][1][r]);
        float gv = ftanh(acc[mt][2][r]);
        float ov = fsig (acc[mt][3][r]);
        float &c = cst[mt*4+r];
        c = fv*c + iv*gv;
        float hval = ov*ftanh(c);
        out[((size_t)b*T_STEPS + tout)*(2*UNITS) + outcol] = hval;
        if (t == T_STEPS-1)
          out[(size_t)BATCH*T_STEPS*(2*UNITS) + (size_t)b*(2*UNITS) + outcol] = hval;
        _Float16 hf = (_Float16)hval;
        *(_Float16*)(hnx + swz(b, upl)) = hf;
        if (t+1 < T_STEPS)
          __hip_atomic_store(&slc[b*64 + (w*16+l15)],
                             __builtin_bit_cast(unsigned short, hf),
                             __ATOMIC_RELAXED, __HIP_MEMORY_SCOPE_AGENT);
      }
    }
    __syncthreads();

    if (t+1 < T_STEPS){
      if (tid == 192)
        __hip_atomic_store(&flags[(dir*4+g4)*32], (unsigned)(t+1),
                           __ATOMIC_RELAXED, __HIP_MEMORY_SCOPE_AGENT);
#pragma unroll
      for (int j=0;j<4;j++){
        half8 hh;
#pragma unroll
        for (int e=0;e<8;e++) hh[e] = (_Float16)xr[j*8+e];
        *(half8*)((char*)xlds + swz(bx, d0x + j*8)) = hh;
      }
      if (w < 3){
        const int p = w + (w >= g4);
        const unsigned target = (unsigned)(t+1);
        if (spin_ok){
          int sp = 0;
          while (__hip_atomic_load(&flags[(dir*4+p)*32],
                                   __ATOMIC_RELAXED, __HIP_MEMORY_SCOPE_AGENT) < target){
            if (++sp > (1<<22)) { spin_ok = false; break; }
          }
        }
        const ull* src = (const ull*)(slices + (((size_t)((t+1)&1))*8 + dir*4 + p)*2048);
        const int bsl = lane >> 1;
        const int u00 = (lane & 1) * 32;
#pragma unroll
        for (int j=0;j<4;j++){
          ull v0 = __hip_atomic_load(&src[lane*8 + 2*j  ], __ATOMIC_RELAXED, __HIP_MEMORY_SCOPE_AGENT);
          ull v1 = __hip_atomic_load(&src[lane*8 + 2*j+1], __ATOMIC_RELAXED, __HIP_MEMORY_SCOPE_AGENT);
          ull2 vv; vv[0]=v0; vv[1]=v1;
          *(ull2*)(hnx + swz(bsl, p*64 + u00 + j*8)) = vv;
        }
      }
      __syncthreads();
    }
  }
}

extern "C" void kernel_launch(void* const* d_in, const int* in_sizes, int n_in,
                              void* d_out, int out_size, void* d_ws, size_t ws_size,
                              hipStream_t stream) {
  const float* x    = (const float*)d_in[0];
  const float* Wk_f = (const float*)d_in[1];
  const float* Wr_f = (const float*)d_in[2];
  const float* b_f  = (const float*)d_in[3];
  const float* Wk_b = (const float*)d_in[4];
  const float* Wr_b = (const float*)d_in[5];
  const float* b_b  = (const float*)d_in[6];
  float* out = (float*)d_out;

  const size_t XPH = (size_t)2*T_STEPS*COLS4U*BATCH*sizeof(_Float16);  // 64 MiB
  const size_t RPB = (size_t)2*8*4096*8*sizeof(_Float16);              // 1 MiB

  if (ws_size >= XPH + RPB) {
    _Float16* xph = (_Float16*)d_ws;
    _Float16* rp  = (_Float16*)((char*)d_ws + XPH);
    repack<<<256, 256, 0, stream>>>(Wr_f, Wr_b, rp);
    xproj<<<512, 256, 0, stream>>>(x, Wk_f, b_f, Wk_b, b_b, xph);
    bilstm_bsplit<<<4, 256, 0, stream>>>(rp, out, xph);
  } else {
    unsigned short* slices = (unsigned short*)d_ws;
    unsigned* flags = (unsigned*)((char*)d_ws + 65536);
    hipMemsetAsync((char*)d_ws + 65536, 0, 1024, stream);
    bilstm_mfma<<<8, 256, 0, stream>>>(x, Wk_f, Wr_f, b_f, Wk_b, Wr_b, b_b,
                                       out, slices, flags);
  }
}

// Round 10
// 5982.139 us; speedup vs baseline: 1.5890x; 1.2555x over previous
//
#include <hip/hip_runtime.h>

#define T_STEPS 512
#define BATCH   32
#define DIM     256
#define UNITS   256
#define COLS4U  1024

typedef _Float16 half8  __attribute__((ext_vector_type(8)));
typedef _Float16 half4v __attribute__((ext_vector_type(4)));
typedef float    f32x4  __attribute__((ext_vector_type(4)));
typedef unsigned long long ull;
typedef ull      ull2   __attribute__((ext_vector_type(2)));
typedef unsigned int u32;

__device__ __forceinline__ float fsig(float x){ return 1.0f/(1.0f+__expf(-x)); }
__device__ __forceinline__ float ftanh(float x){
  float xx=fminf(fmaxf(x,-15.f),15.f);
  float e=__expf(2.f*xx);
  return (e-1.f)/(e+1.f);
}
// byte offset into a [rows][256] f16 LDS plane, XOR-swizzled 16B granules (proven r2/r3)
__device__ __forceinline__ int swz(int b,int u){
  int g=u>>3; int s=(g&7)^(b&7);
  return b*512 + (g>>3)*128 + s*16 + (u&7)*2;
}

// async global->LDS, 16B per lane; LDS dest = wave-uniform base + lane*16
__device__ __forceinline__ void gl_lds16(const void* g, void* l){
  __builtin_amdgcn_global_load_lds(
      (const __attribute__((address_space(1))) u32*)g,
      (__attribute__((address_space(3))) u32*)l, 16, 0, 0);
}

// ============================================================================
// repack2: rp2 granule idx = ((((dir*8+kt)*4+w)*16+nt)*4+l4)*16+l15  (16B each)
//   granule = Wr[kt*32+l4*8 .. +8][col],  col = (nt>>2)*256 + w*64 + (nt&3)*16 + l15
// Per (kt,w): contiguous 16 KB chunk, linear in (nt, l4, l15) = lane order.
// ============================================================================
__global__ __launch_bounds__(256) void repack2(
    const float* __restrict__ Wr_f, const float* __restrict__ Wr_b,
    _Float16* __restrict__ rp2)
{
  const int idx = blockIdx.x*256 + threadIdx.x;   // 65536 granules
  const int l15 = idx & 15;
  const int l4  = (idx>>4) & 3;
  const int nt  = (idx>>6) & 15;
  const int w   = (idx>>10) & 3;
  const int kt  = (idx>>12) & 7;
  const int dir = idx >> 15;
  const float* Wr = dir ? Wr_b : Wr_f;
  const int col = (nt>>2)*256 + w*64 + (nt&3)*16 + l15;
  const int k0  = kt*32 + l4*8;
  half8 v;
#pragma unroll
  for (int r=0;r<8;r++) v[r] = (_Float16)Wr[(size_t)(k0+r)*COLS4U + col];
  *(half8*)(rp2 + ((size_t)idx<<3)) = v;
}

// ============================================================================
// Phase 1 (r3-proven, verbatim): xp[dir][t][col][b] fp16 = b + x@Wk
// ============================================================================
__global__ __launch_bounds__(256, 2) void xproj(
    const float* __restrict__ x,
    const float* __restrict__ Wk_f, const float* __restrict__ b_f,
    const float* __restrict__ Wk_b, const float* __restrict__ b_b,
    _Float16* __restrict__ xph)
{
  const int bx  = blockIdx.x;
  const int dir = bx >> 8;
  const int cg  = (bx >> 5) & 7;
  const int tg  = bx & 31;
  const int tid = threadIdx.x;
  const int w   = tid >> 6;
  const int lane= tid & 63;
  const int l15 = lane & 15;
  const int l4  = lane >> 4;

  const float* Wk = dir ? Wk_b : Wk_f;
  const float* bs = dir ? b_b  : b_f;

  const int col0 = cg*128 + w*32;

  half8 Bf[2][8];
  float bias[2];
#pragma unroll
  for (int nt=0; nt<2; nt++){
    const int col = col0 + nt*16 + l15;
    bias[nt] = bs[col];
#pragma unroll
    for (int kk=0; kk<8; kk++){
      half8 v;
#pragma unroll
      for (int r=0; r<8; r++) v[r] = (_Float16)Wk[(size_t)(kk*32 + l4*8 + r)*COLS4U + col];
      Bf[nt][kk] = v;
    }
  }

  for (int tt=0; tt<16; ++tt){
    const int t   = tg*16 + tt;
    const int tin = dir ? (T_STEPS-1-t) : t;

    half8 Af[2][8];
#pragma unroll
    for (int mt=0; mt<2; mt++){
      const int b = mt*16 + l15;
#pragma unroll
      for (int kk=0; kk<8; kk++){
        const float* xp_ = x + ((size_t)b*T_STEPS + tin)*DIM + kk*32 + l4*8;
        f32x4 u0 = *(const f32x4*)xp_;
        f32x4 u1 = *(const f32x4*)(xp_ + 4);
        half8 v;
        v[0]=(_Float16)u0[0]; v[1]=(_Float16)u0[1]; v[2]=(_Float16)u0[2]; v[3]=(_Float16)u0[3];
        v[4]=(_Float16)u1[0]; v[5]=(_Float16)u1[1]; v[6]=(_Float16)u1[2]; v[7]=(_Float16)u1[3];
        Af[mt][kk] = v;
      }
    }

    f32x4 acc[2][2];
#pragma unroll
    for (int nt=0; nt<2; nt++){
      f32x4 a; a[0]=bias[nt]; a[1]=bias[nt]; a[2]=bias[nt]; a[3]=bias[nt];
      acc[nt][0]=a; acc[nt][1]=a;
    }
#pragma unroll
    for (int kk=0; kk<8; kk++)
#pragma unroll
      for (int nt=0; nt<2; nt++)
#pragma unroll
        for (int mt=0; mt<2; mt++)
          acc[nt][mt] = __builtin_amdgcn_mfma_f32_16x16x32_f16(Af[mt][kk], Bf[nt][kk], acc[nt][mt], 0,0,0);

#pragma unroll
    for (int nt=0; nt<2; nt++){
      const int col = col0 + nt*16 + l15;
#pragma unroll
      for (int mt=0; mt<2; mt++){
        half4v o;
        o[0]=(_Float16)acc[nt][mt][0]; o[1]=(_Float16)acc[nt][mt][1];
        o[2]=(_Float16)acc[nt][mt][2]; o[3]=(_Float16)acc[nt][mt][3];
        *(ull*)(xph + ((size_t)(dir*T_STEPS + t)*COLS4U + col)*BATCH + mt*16 + l4*4)
            = __builtin_bit_cast(ull, o);
      }
    }
  }
}

// ============================================================================
// Phase 2: batch-split scan, async-LDS weight streaming.
// 4 blocks (dir x bh), 256 thr. kt0 regs; kt1..7 streamed via global_load_lds
// into per-wave double-buffered 16KB chunks; wave-local vmcnt(16) sync only.
// ============================================================================
__global__ __launch_bounds__(256, 1) void bilstm_async(
    const _Float16* __restrict__ rp2,
    float* __restrict__ out,
    const _Float16* __restrict__ xph)
{
  const int dir = (int)blockIdx.x >> 1;
  const int bh  = (int)blockIdx.x & 1;
  const int tid = threadIdx.x;
  const int w   = tid >> 6;         // 0..3
  const int lane= tid & 63;
  const int l15 = lane & 15;
  const int l4  = lane >> 4;

  __shared__ _Float16 dstr[2][4][8192];  // 2 x 4 waves x 16 KB = 128 KB
  __shared__ _Float16 hpl[16*UNITS];     // 8 KB, swizzled h plane

  // chunk base (bytes) in rp2 for (kt, this wave)
  const char* rpb = (const char*)rp2 + ((size_t)dir*8*4)*16384 + (size_t)w*16384;
  // per-plane stride = 4 chunks * 16 KB
#define PLANE(kt) (rpb + (size_t)(kt)*4*16384)

  int col[16];
#pragma unroll
  for (int nt=0; nt<16; nt++)
    col[nt] = (nt>>2)*256 + w*64 + (nt&3)*16 + l15;

  // --- kt0 fragments in registers ---
  half8 Bf[16];
#pragma unroll
  for (int nt=0; nt<16; nt++)
    Bf[nt] = *(const half8*)(PLANE(0) + (size_t)(nt*64 + l4*16 + l15)*16);

  // --- h = 0 ---
  for (int i=tid; i<1024; i+=256) ((ull*)hpl)[i] = 0ull;
  __syncthreads();

  float cst[16];
#pragma unroll
  for (int i=0;i<16;i++) cst[i]=0.f;

  const _Float16* xpt = xph + (size_t)dir*T_STEPS*COLS4U*BATCH + bh*16;

  // --- prologue: xp(0) regs + plane kt1 -> dbuf[1] ---
  ull xpv[16];
#pragma unroll
  for (int nt=0; nt<16; nt++)
    xpv[nt] = *(const ull*)(xpt + (size_t)0*32768 + col[nt]*32 + l4*4);

  {
    char* d = (char*)&dstr[1][w][0];
#pragma unroll
    for (int i=0;i<16;i++)
      gl_lds16(PLANE(1) + i*1024 + lane*16, d + i*1024);
  }

  for (int t=0; t<T_STEPS; ++t){
    // ---- acc init from xpv; prefetch xp(t+1) (clamped at tail) ----
    f32x4 acc[16];
#pragma unroll
    for (int nt=0; nt<16; nt++){
      half4v hv = __builtin_bit_cast(half4v, xpv[nt]);
      f32x4 a; a[0]=(float)hv[0]; a[1]=(float)hv[1]; a[2]=(float)hv[2]; a[3]=(float)hv[3];
      acc[nt] = a;
    }

    // ---- h fragments for all 8 ktiles (after barrier; LDS-local) ----
    half8 a0v[8];
#pragma unroll
    for (int kt=0; kt<8; kt++)
      a0v[kt] = *(const half8*)((const char*)hpl + swz(l15, kt*32 + l4*8));

    // ---- kt0 from registers ----
#pragma unroll
    for (int nt=0; nt<16; nt++)
      acc[nt] = __builtin_amdgcn_mfma_f32_16x16x32_f16(a0v[0], Bf[nt], acc[nt], 0,0,0);

    // ---- kt1..7 streamed: issue kt(s+1), wait kt(s), consume kt(s) ----
#pragma unroll
    for (int s=1; s<8; ++s){
      if (s < 7){
        char* d = (char*)&dstr[(s+1)&1][w][0];
#pragma unroll
        for (int i=0;i<16;i++)
          gl_lds16(PLANE(s+1) + i*1024 + lane*16, d + i*1024);
      } else {
        // xp(t+1) prefetch goes into the queue behind kt7
        const int tn = (t+1 < T_STEPS) ? (t+1) : t;
#pragma unroll
        for (int nt=0; nt<16; nt++)
          xpv[nt] = *(const ull*)(xpt + (size_t)tn*32768 + col[nt]*32 + l4*4);
      }
      asm volatile("s_waitcnt vmcnt(16)" ::: "memory");
      __builtin_amdgcn_sched_barrier(0);
      const char* d = (const char*)&dstr[s&1][w][0];
#pragma unroll
      for (int nt=0; nt<16; nt++){
        half8 bs = *(const half8*)(d + (size_t)(nt*64 + l4*16 + l15)*16);
        acc[nt] = __builtin_amdgcn_mfma_f32_16x16x32_f16(a0v[s], bs, acc[nt], 0,0,0);
      }
    }

    // ---- re-issue next step's kt1 (weights are t-independent; idempotent) ----
    {
      char* d = (char*)&dstr[1][w][0];
#pragma unroll
      for (int i=0;i<16;i++)
        gl_lds16(PLANE(1) + i*1024 + lane*16, d + i*1024);
    }

    __syncthreads();   // all waves done reading h_t

    // ---- gates -> c, h ; write h_{t+1} + out ----
    const int tout = dir ? (T_STEPS-1-t) : t;
#pragma unroll
    for (int j=0; j<4; j++){
      const int unit = w*64 + j*16 + l15;
      const int oc   = dir*256 + unit;
#pragma unroll
      for (int r=0; r<4; r++){
        const int b = l4*4 + r;                 // local batch row 0..15
        float iv = fsig (acc[0*4+j][r]);
        float fv = fsig (acc[1*4+j][r]);
        float gv = ftanh(acc[2*4+j][r]);
        float ov = fsig (acc[3*4+j][r]);
        float &c = cst[j*4+r];
        c = fv*c + iv*gv;
        float hv = ov*ftanh(c);
        if (t+1 < T_STEPS)
          *(_Float16*)((char*)hpl + swz(b, unit)) = (_Float16)hv;
        const size_t B = (size_t)(bh*16 + b);
        out[(B*T_STEPS + tout)*(2*UNITS) + oc] = hv;
        if (t == T_STEPS-1)
          out[(size_t)BATCH*T_STEPS*(2*UNITS) + B*(2*UNITS) + oc] = hv;
      }
    }
    __syncthreads();   // h_{t+1} complete before next step's reads
  }
#undef PLANE
}

// ============================================================================
// Fallback for small ws (round-2 proven fused kernel)
// ============================================================================
__global__ __launch_bounds__(256,1) void bilstm_mfma(
    const float* __restrict__ x,
    const float* __restrict__ Wk_f, const float* __restrict__ Wr_f, const float* __restrict__ b_f,
    const float* __restrict__ Wk_b, const float* __restrict__ Wr_b, const float* __restrict__ b_b,
    float* __restrict__ out,
    unsigned short* __restrict__ slices,
    unsigned* __restrict__ flags)
{
  const int dir = blockIdx.x >> 2;
  const int g4  = blockIdx.x & 3;
  const int tid = threadIdx.x;
  const int w   = tid >> 6;
  const int lane= tid & 63;
  const int l15 = lane & 15;
  const int l4  = lane >> 4;

  const float* Wk = dir ? Wk_b : Wk_f;
  const float* Wr = dir ? Wr_b : Wr_f;
  const float* bs = dir ? b_b  : b_f;

  const int u0b   = g4*64;
  const int upl   = u0b + w*16 + l15;
  const int outcol= dir*256 + upl;

  __shared__ _Float16 xlds[BATCH*DIM];
  __shared__ _Float16 hlds[2][BATCH*UNITS];

  half8 Bf[4][16];
#pragma unroll
  for (int q=0;q<4;q++){
    const int col = q*256 + upl;
#pragma unroll
    for (int kk=0;kk<16;kk++){
      const float* Ws = (kk<8) ? Wk : Wr;
      const int k0 = (kk&7)*32 + l4*8;
      half8 v;
#pragma unroll
      for (int r=0;r<8;r++) v[r] = (_Float16)Ws[(size_t)(k0+r)*COLS4U + col];
      Bf[q][kk] = v;
      __builtin_amdgcn_sched_barrier(0);
    }
  }

  float bias[4];
#pragma unroll
  for (int q=0;q<4;q++) bias[q] = bs[q*256 + upl];

  {
    half8 z;
#pragma unroll
    for (int e=0;e<8;e++) z[e] = (_Float16)0.f;
    for (int i=tid; i<BATCH*UNITS/8; i+=256) ((half8*)hlds[0])[i] = z;
  }

  const int bx  = tid >> 3;
  const int d0x = (tid & 7) * 32;
  float xr[32];
  {
    const int tin0 = dir ? (T_STEPS-1) : 0;
    const float* xp = x + ((size_t)bx*T_STEPS + tin0)*DIM + d0x;
#pragma unroll
    for (int i=0;i<8;i++){
      f32x4 v = *(const f32x4*)(xp + i*4);
      xr[i*4+0]=v[0]; xr[i*4+1]=v[1]; xr[i*4+2]=v[2]; xr[i*4+3]=v[3];
    }
#pragma unroll
    for (int j=0;j<4;j++){
      half8 hh;
#pragma unroll
      for (int e=0;e<8;e++) hh[e] = (_Float16)xr[j*8+e];
      *(half8*)((char*)xlds + swz(bx, d0x + j*8)) = hh;
    }
  }
  __syncthreads();

  float cst[8];
#pragma unroll
  for (int i=0;i<8;i++) cst[i]=0.f;
  bool spin_ok = true;

  for (int t=0; t<T_STEPS; ++t){
    if (t+1 < T_STEPS){
      const int tin = dir ? (T_STEPS-2-t) : (t+1);
      const float* xp = x + ((size_t)bx*T_STEPS + tin)*DIM + d0x;
#pragma unroll
      for (int i=0;i<8;i++){
        f32x4 v = *(const f32x4*)(xp + i*4);
        xr[i*4+0]=v[0]; xr[i*4+1]=v[1]; xr[i*4+2]=v[2]; xr[i*4+3]=v[3];
      }
    }

    f32x4 acc[2][4];
#pragma unroll
    for (int q=0;q<4;q++){
      f32x4 a; a[0]=bias[q]; a[1]=bias[q]; a[2]=bias[q]; a[3]=bias[q];
      acc[0][q]=a; acc[1][q]=a;
    }
    const char* hpl2 = (const char*)hlds[t&1];
#pragma unroll
    for (int kk=0;kk<16;kk++){
      const char* pl = (kk<8) ? (const char*)xlds : hpl2;
      const int ul = (kk&7)*32 + l4*8;
      half8 a0 = *(const half8*)(pl + swz(l15,      ul));
      half8 a1 = *(const half8*)(pl + swz(16+l15,   ul));
#pragma unroll
      for (int q=0;q<4;q++){
        acc[0][q] = __builtin_amdgcn_mfma_f32_16x16x32_f16(a0, Bf[q][kk], acc[0][q], 0,0,0);
        acc[1][q] = __builtin_amdgcn_mfma_f32_16x16x32_f16(a1, Bf[q][kk], acc[1][q], 0,0,0);
      }
    }

    const int tout = dir ? (T_STEPS-1-t) : t;
    unsigned short* slc = slices + (((size_t)((t+1)&1))*8 + dir*4 + g4)*2048;
    char* hnx = (char*)hlds[(t+1)&1];
#pragma unroll
    for (int mt=0; mt<2; mt++){
#pragma unroll
      for (int r=0;r<4;r++){
        const int b = mt*16 + l4*4 + r;
        float iv = fsig (acc[mt][0][r]);
        float fv = fsig (acc[mt][1][r]);
        float gv = ftanh(acc[mt][2][r]);
        float ov = fsig (acc[mt][3][r]);
        float &c = cst[mt*4+r];
        c = fv*c + iv*gv;
        float hval = ov*ftanh(c);
        out[((size_t)b*T_STEPS + tout)*(2*UNITS) + outcol] = hval;
        if (t == T_STEPS-1)
          out[(size_t)BATCH*T_STEPS*(2*UNITS) + (size_t)b*(2*UNITS) + outcol] = hval;
        _Float16 hf = (_Float16)hval;
        *(_Float16*)(hnx + swz(b, upl)) = hf;
        if (t+1 < T_STEPS)
          __hip_atomic_store(&slc[b*64 + (w*16+l15)],
                             __builtin_bit_cast(unsigned short, hf),
                             __ATOMIC_RELAXED, __HIP_MEMORY_SCOPE_AGENT);
      }
    }
    __syncthreads();

    if (t+1 < T_STEPS){
      if (tid == 192)
        __hip_atomic_store(&flags[(dir*4+g4)*32], (unsigned)(t+1),
                           __ATOMIC_RELAXED, __HIP_MEMORY_SCOPE_AGENT);
#pragma unroll
      for (int j=0;j<4;j++){
        half8 hh;
#pragma unroll
        for (int e=0;e<8;e++) hh[e] = (_Float16)xr[j*8+e];
        *(half8*)((char*)xlds + swz(bx, d0x + j*8)) = hh;
      }
      if (w < 3){
        const int p = w + (w >= g4);
        const unsigned target = (unsigned)(t+1);
        if (spin_ok){
          int sp = 0;
          while (__hip_atomic_load(&flags[(dir*4+p)*32],
                                   __ATOMIC_RELAXED, __HIP_MEMORY_SCOPE_AGENT) < target){
            if (++sp > (1<<22)) { spin_ok = false; break; }
          }
        }
        const ull* src = (const ull*)(slices + (((size_t)((t+1)&1))*8 + dir*4 + p)*2048);
        const int bsl = lane >> 1;
        const int u00 = (lane & 1) * 32;
#pragma unroll
        for (int j=0;j<4;j++){
          ull v0 = __hip_atomic_load(&src[lane*8 + 2*j  ], __ATOMIC_RELAXED, __HIP_MEMORY_SCOPE_AGENT);
          ull v1 = __hip_atomic_load(&src[lane*8 + 2*j+1], __ATOMIC_RELAXED, __HIP_MEMORY_SCOPE_AGENT);
          ull2 vv; vv[0]=v0; vv[1]=v1;
          *(ull2*)(hnx + swz(bsl, p*64 + u00 + j*8)) = vv;
        }
      }
      __syncthreads();
    }
  }
}

extern "C" void kernel_launch(void* const* d_in, const int* in_sizes, int n_in,
                              void* d_out, int out_size, void* d_ws, size_t ws_size,
                              hipStream_t stream) {
  const float* x    = (const float*)d_in[0];
  const float* Wk_f = (const float*)d_in[1];
  const float* Wr_f = (const float*)d_in[2];
  const float* b_f  = (const float*)d_in[3];
  const float* Wk_b = (const float*)d_in[4];
  const float* Wr_b = (const float*)d_in[5];
  const float* b_b  = (const float*)d_in[6];
  float* out = (float*)d_out;

  const size_t XPH = (size_t)2*T_STEPS*COLS4U*BATCH*sizeof(_Float16);  // 64 MiB
  const size_t RPB = (size_t)65536*16;                                 // 1 MiB

  if (ws_size >= XPH + RPB) {
    _Float16* xph = (_Float16*)d_ws;
    _Float16* rp2 = (_Float16*)((char*)d_ws + XPH);
    repack2<<<256, 256, 0, stream>>>(Wr_f, Wr_b, rp2);
    xproj<<<512, 256, 0, stream>>>(x, Wk_f, b_f, Wk_b, b_b, xph);
    bilstm_async<<<4, 256, 0, stream>>>(rp2, out, xph);
  } else {
    unsigned short* slices = (unsigned short*)d_ws;
    unsigned* flags = (unsigned*)((char*)d_ws + 65536);
    hipMemsetAsync((char*)d_ws + 65536, 0, 1024, stream);
    bilstm_mfma<<<8, 256, 0, stream>>>(x, Wk_f, Wr_f, b_f, Wk_b, Wr_b, b_b,
                                       out, slices, flags);
  }
}